// Round 7
// baseline (110.028 us; speedup 1.0000x reference)
//
#include <hip/hip_runtime.h>
#include <math.h>

#define BATCH 4
#define SEQ   1024
#define HID   512
#define NHEAD 8

typedef unsigned short u16;
typedef unsigned int   u32;
typedef short  short8 __attribute__((ext_vector_type(8)));
typedef float  f32x4  __attribute__((ext_vector_type(4)));

__device__ __forceinline__ u16 f2bf(float x) {
  u32 u = __builtin_bit_cast(u32, x);
  u32 r = (u + 0x7FFFu + ((u >> 16) & 1u)) >> 16;
  return (u16)r;
}

// max-reduce over the 16 lanes of a row via DPP (VALU only, no DS ops)
#define DPPMAX(x, ctrl)                                                        \
  x = fmaxf(x, __builtin_bit_cast(float, __builtin_amdgcn_update_dpp(          \
                   0, __builtin_bit_cast(int, x), ctrl, 0xf, 0xf, true)))

// ---------------- fp32 -> bf16 convert: x (524288 float4s) then pe (262016) --
__global__ __launch_bounds__(256)
void cvt_two(const float* __restrict__ x, const float* __restrict__ pe,
             u16* __restrict__ xb, u16* __restrict__ peb) {
  int i = blockIdx.x * 256 + threadIdx.x;
  const float* s;
  u16* d;
  if (i < 524288) {
    s = x; d = xb;
  } else {
    i -= 524288;
    if (i >= 262016) return;
    s = pe; d = peb;
  }
  float4 v = *(const float4*)&s[(size_t)i * 4];
  ushort4 o;
  o.x = f2bf(v.x); o.y = f2bf(v.y); o.z = f2bf(v.z); o.w = f2bf(v.w);
  *(ushort4*)&d[(size_t)i * 4] = o;
}

// ---------------- W (512x512 f32 k-major) -> Wt (n-major bf16), 5 mats -------
__global__ __launch_bounds__(256)
void transpose_w(const float* w0, const float* w1, const float* w2,
                 const float* w3, const float* w4, u16* __restrict__ wt) {
  const float* src;
  switch (blockIdx.z) {
    case 0: src = w0; break;
    case 1: src = w1; break;
    case 2: src = w2; break;
    case 3: src = w3; break;
    default: src = w4; break;
  }
  u16* dst = wt + (size_t)blockIdx.z * 512 * 512;
  __shared__ float t[32][33];
  const int tx = threadIdx.x, ty = threadIdx.y;  // block (32,8)
  const int k0 = blockIdx.x * 32, n0 = blockIdx.y * 32;
#pragma unroll
  for (int r = 0; r < 4; ++r)
    t[ty + 8 * r][tx] = src[(size_t)(k0 + ty + 8 * r) * 512 + n0 + tx];
  __syncthreads();
#pragma unroll
  for (int r = 0; r < 4; ++r)
    dst[(size_t)(n0 + ty + 8 * r) * 512 + k0 + tx] = f2bf(t[tx][ty + 8 * r]);
}

// ---------------- MFMA GEMM core: acc = A[BMx512] @ Bt^T tile ---------------
template <int MF, int NF>
__device__ __forceinline__ void gemm_core(const u16* __restrict__ A,
                                          const u16* __restrict__ Bt,
                                          int m0, int n0, u16* As, u16* Bs,
                                          f32x4 (&acc)[MF][NF]) {
  const int tid = threadIdx.x;
  const int wid = tid >> 6, lane = tid & 63;
  const int lr = lane & 15, lg = lane >> 4;
  const int wm = wid >> 1, wn = wid & 1;
  const int srow = tid >> 3, sc = tid & 7;
#pragma unroll
  for (int i = 0; i < MF; ++i)
#pragma unroll
    for (int j = 0; j < NF; ++j) acc[i][j] = (f32x4)0.f;

  for (int kt = 0; kt < 8; ++kt) {
    const int k0 = kt * 64;
    short8 la[MF], lb[NF];
#pragma unroll
    for (int r = 0; r < MF; ++r)
      la[r] = *(const short8*)&A[(size_t)(m0 + srow + 32 * r) * 512 + k0 + sc * 8];
#pragma unroll
    for (int r = 0; r < NF; ++r)
      lb[r] = *(const short8*)&Bt[(size_t)(n0 + srow + 32 * r) * 512 + k0 + sc * 8];
    __syncthreads();
#pragma unroll
    for (int r = 0; r < MF; ++r) {
      int row = srow + 32 * r;
      *(short8*)&As[row * 64 + ((sc ^ (row & 7)) * 8)] = la[r];
    }
#pragma unroll
    for (int r = 0; r < NF; ++r) {
      int row = srow + 32 * r;
      *(short8*)&Bs[row * 64 + ((sc ^ (row & 7)) * 8)] = lb[r];
    }
    __syncthreads();
#pragma unroll
    for (int kc = 0; kc < 2; ++kc) {
      const int ch = kc * 4 + lg;
      short8 af[MF], bfr[NF];
#pragma unroll
      for (int mt = 0; mt < MF; ++mt) {
        int row = wm * (MF * 16) + mt * 16 + lr;
        af[mt] = *(const short8*)&As[row * 64 + ((ch ^ (row & 7)) * 8)];
      }
#pragma unroll
      for (int nt = 0; nt < NF; ++nt) {
        int row = wn * (NF * 16) + nt * 16 + lr;
        bfr[nt] = *(const short8*)&Bs[row * 64 + ((ch ^ (row & 7)) * 8)];
      }
#pragma unroll
      for (int mt = 0; mt < MF; ++mt)
#pragma unroll
        for (int nt = 0; nt < NF; ++nt)
          acc[mt][nt] = __builtin_amdgcn_mfma_f32_16x16x32_bf16(
              af[mt], bfr[nt], acc[mt][nt], 0, 0, 0);
    }
  }
}

// ---------------- fused Q/K/V/P projection GEMM (z = 0..3) ------------------
__global__ __launch_bounds__(256)
void gemm_qkvp(const u16* __restrict__ xbf, const u16* __restrict__ pebf,
               const u16* __restrict__ wt,
               const float* __restrict__ bq, const float* __restrict__ bk,
               const float* __restrict__ bv, const float* __restrict__ bp,
               const float* __restrict__ pbu, const float* __restrict__ pbv,
               u16* __restrict__ qu, u16* __restrict__ qv,
               u16* __restrict__ kk, u16* __restrict__ vt,
               u16* __restrict__ pp) {
  __shared__ __align__(16) u16 As[128 * 64];
  __shared__ __align__(16) u16 Bs[128 * 64];
  const int z = blockIdx.z;
  if (z == 3 && blockIdx.y >= 16) return;
  const u16* A = (z == 3) ? pebf : xbf;
  const u16* Bt = wt + (size_t)z * 512 * 512;
  const float* bias = (z == 0) ? bq : (z == 1) ? bk : (z == 2) ? bv : bp;
  const int m0 = blockIdx.y * 128, n0 = blockIdx.x * 128;

  f32x4 acc[4][4];
  gemm_core<4, 4>(A, Bt, m0, n0, As, Bs, acc);

  const int tid = threadIdx.x, wid = tid >> 6, lane = tid & 63;
  const int lr = lane & 15, lg = lane >> 4, wm = wid >> 1, wn = wid & 1;
#pragma unroll
  for (int mt = 0; mt < 4; ++mt)
#pragma unroll
    for (int nt = 0; nt < 4; ++nt) {
      const int col = n0 + wn * 64 + nt * 16 + lr;
      const int rb = m0 + wm * 64 + mt * 16 + lg * 4;
      const float bcol = bias[col];
      if (z == 0) {
        const float uu = pbu[col], vv = pbv[col];
#pragma unroll
        for (int q = 0; q < 4; ++q) {
          float val = acc[mt][nt][q] + bcol;
          qu[(size_t)(rb + q) * 512 + col] = f2bf(val + uu);
          qv[(size_t)(rb + q) * 512 + col] = f2bf(val + vv);
        }
      } else if (z == 1) {
#pragma unroll
        for (int q = 0; q < 4; ++q)
          kk[(size_t)(rb + q) * 512 + col] = f2bf(acc[mt][nt][q] + bcol);
      } else if (z == 2) {
        // V^T layout [b][h][d][t]
        ushort4 pk;
        pk.x = f2bf(acc[mt][nt][0] + bcol);
        pk.y = f2bf(acc[mt][nt][1] + bcol);
        pk.z = f2bf(acc[mt][nt][2] + bcol);
        pk.w = f2bf(acc[mt][nt][3] + bcol);
        int bb = rb >> 10, tl = rb & 1023;
        *(ushort4*)&vt[(size_t)((bb * 8 + (col >> 6)) * 64 + (col & 63)) * 1024 + tl] = pk;
      } else {
#pragma unroll
        for (int q = 0; q < 4; ++q)
          if (rb + q < 2047)
            pp[(size_t)(rb + q) * 512 + col] = f2bf(acc[mt][nt][q] + bcol);
      }
    }
}

// ---------------- output projection: out = ao @ Wo^T + bo (f32) -------------
__global__ __launch_bounds__(256)
void gemm_wo(const u16* __restrict__ ao, const u16* __restrict__ wt,
             const float* __restrict__ bo, float* __restrict__ out) {
  __shared__ __align__(16) u16 As[64 * 64];
  __shared__ __align__(16) u16 Bs[64 * 64];
  const int m0 = blockIdx.y * 64, n0 = blockIdx.x * 64;
  f32x4 acc[2][2];
  gemm_core<2, 2>(ao, wt + (size_t)4 * 512 * 512, m0, n0, As, Bs, acc);
  const int tid = threadIdx.x, wid = tid >> 6, lane = tid & 63;
  const int lr = lane & 15, lg = lane >> 4, wm = wid >> 1, wn = wid & 1;
#pragma unroll
  for (int mt = 0; mt < 2; ++mt)
#pragma unroll
    for (int nt = 0; nt < 2; ++nt) {
      const int col = n0 + wn * 32 + nt * 16 + lr;
      const int rb = m0 + wm * 32 + mt * 16 + lg * 4;
      const float bcol = bo[col];
#pragma unroll
      for (int q = 0; q < 4; ++q)
        out[(size_t)(rb + q) * 512 + col] = acc[mt][nt][q] + bcol;
    }
}

// ---------------- flash rel-pos attention, bf16 MFMA ------------------------
// Block: (b, h, 64 q-rows), 256 thr = 4 waves.
// Waves 0-1 process even j-tiles (rows 0-31 / 32-63), waves 2-3 odd j-tiles.
// Each wave owns 32 rows = 2 frags -> K/V B-frag reads feed 2 MFMAs each.
// P window in a 192-row ring; T14 async staging; LDS merge of the j-halves.
__global__ __launch_bounds__(256)
void attn_mfma(const u16* __restrict__ quP, const u16* __restrict__ qvP,
               const u16* __restrict__ kP, const u16* __restrict__ vtP,
               const u16* __restrict__ pP, u16* __restrict__ ao) {
  __shared__ __align__(16) u16 Ks[2][4096];   // [jtile][64x64] swz
  __shared__ __align__(16) u16 Vs[2][4096];   // [jtile][64x64] V^T swz
  __shared__ __align__(16) u16 Ps[192 * 64];  // ring, swz
  __shared__ __align__(16) float Wb[4][1504]; // per-wave Bds(stride 94)/Es overlay

  const int tid = threadIdx.x;
  const int wid = tid >> 6, lane = tid & 63;
  const int lr = lane & 15, lg = lane >> 4;
  const int grp = wid >> 1, wq = wid & 1;   // j-group, row-group
  const int t0 = blockIdx.x * 64, h = blockIdx.y, b = blockIdx.z;
  const int base0 = 960 - t0;

  float* wb = &Wb[wid][0];
  u16* esw = (u16*)wb;

  // Q fragments: frag f covers rows t0 + 32*wq + 16*f .. +15
  short8 aqu[2][2], aqv[2][2];
#pragma unroll
  for (int f = 0; f < 2; ++f)
#pragma unroll
    for (int kc = 0; kc < 2; ++kc) {
      size_t g = (size_t)(b * SEQ + t0 + 32 * wq + 16 * f + lr) * 512 + h * 64 +
                 kc * 32 + lg * 8;
      aqu[f][kc] = *(const short8*)&quP[g];
      aqv[f][kc] = *(const short8*)&qvP[g];
    }
  short8 ones;
#pragma unroll
  for (int i = 0; i < 8; ++i) ones[i] = (short)0x3F80;  // bf16 1.0

  float mrun[2][4];
  f32x4 cL[2], cO[2][4];
#pragma unroll
  for (int f = 0; f < 2; ++f) {
    cL[f] = (f32x4)0.f;
#pragma unroll
    for (int q = 0; q < 4; ++q) mrun[f][q] = -1e30f;
#pragma unroll
    for (int nt = 0; nt < 4; ++nt) cO[f][nt] = (f32x4)0.f;
  }

  // ---- prologue staging: K/V rows 0..127, P ring rows 0..191 ----
#pragma unroll
  for (int r = 0; r < 4; ++r) {
    int idx = tid + 256 * r;
    int row = idx >> 3, sc = idx & 7;
    short8 lk = *(const short8*)&kP[(size_t)(b * SEQ + row) * 512 + h * 64 + sc * 8];
    short8 lv = *(const short8*)&vtP[(size_t)((b * 8 + h) * 64 + (row & 63)) * 1024 +
                                     (row >> 6) * 64 + sc * 8];
    *(short8*)&Ks[row >> 6][(row & 63) * 64 + ((sc ^ (row & 7)) * 8)] = lk;
    *(short8*)&Vs[row >> 6][(row & 63) * 64 + ((sc ^ (row & 7)) * 8)] = lv;
  }
#pragma unroll
  for (int r = 0; r < 6; ++r) {
    int idx = tid + 256 * r;
    int prow = idx >> 3, sc = idx & 7;
    short8 lp = *(const short8*)&pP[(size_t)(base0 + prow) * 512 + h * 64 + sc * 8];
    *(short8*)&Ps[prow * 64 + ((sc ^ (prow & 7)) * 8)] = lp;
  }
  __syncthreads();

  int jb_self = 64 * grp;  // (j0 of this group) mod 192
  int jbs = 0;             // (128*s) mod 192 (staging ring base)

  for (int s = 0; s < 8; ++s) {
    // ---- T14: issue next superstep's global loads early ----
    short8 nk[4], nv[4], np[4];
    if (s < 7) {
      const int jn = 128 * (s + 1);
#pragma unroll
      for (int r = 0; r < 4; ++r) {
        int idx = tid + 256 * r;
        int row = idx >> 3, sc = idx & 7;
        nk[r] = *(const short8*)&kP[(size_t)(b * SEQ + jn + row) * 512 + h * 64 + sc * 8];
        nv[r] = *(const short8*)&vtP[(size_t)((b * 8 + h) * 64 + (row & 63)) * 1024 +
                                     jn + (row >> 6) * 64 + sc * 8];
        np[r] = *(const short8*)&pP[(size_t)(1152 - t0 + 128 * s + row) * 512 +
                                    h * 64 + sc * 8];
      }
    }

    // ---- compute: S = 0.125*(Qu.K^T + shift(Qv.P^T)); online softmax; O += E.V
    f32x4 cK[2][4];
#pragma unroll
    for (int f = 0; f < 2; ++f)
#pragma unroll
      for (int nt = 0; nt < 4; ++nt) cK[f][nt] = (f32x4)0.f;
    __builtin_amdgcn_s_setprio(1);
#pragma unroll
    for (int kc = 0; kc < 2; ++kc) {
      const int ch = kc * 4 + lg;
#pragma unroll
      for (int nt = 0; nt < 4; ++nt) {
        int krow = nt * 16 + lr;
        short8 bk = *(const short8*)&Ks[grp][krow * 64 + ((ch ^ (krow & 7)) * 8)];
        cK[0][nt] = __builtin_amdgcn_mfma_f32_16x16x32_bf16(aqu[0][kc], bk, cK[0][nt], 0, 0, 0);
        cK[1][nt] = __builtin_amdgcn_mfma_f32_16x16x32_bf16(aqu[1][kc], bk, cK[1][nt], 0, 0, 0);
      }
    }
    __builtin_amdgcn_s_setprio(0);

#pragma unroll
    for (int f = 0; f < 2; ++f) {
      const int gg = 2 * wq + f;
      f32x4 cP5[5];
#pragma unroll
      for (int i = 0; i < 5; ++i) cP5[i] = (f32x4)0.f;
      __builtin_amdgcn_s_setprio(1);
#pragma unroll
      for (int kc = 0; kc < 2; ++kc) {
        const int ch = kc * 4 + lg;
        const int swz = (ch ^ (lr & 7)) * 8;
#pragma unroll
        for (int pt = 0; pt < 5; ++pt) {
          int pr = jb_self + (3 - gg + pt) * 16 + lr;
          if (pr >= 192) pr -= 192;
          short8 bp = *(const short8*)&Ps[pr * 64 + swz];
          cP5[pt] = __builtin_amdgcn_mfma_f32_16x16x32_bf16(aqv[f][kc], bp, cP5[pt], 0, 0, 0);
        }
      }
      __builtin_amdgcn_s_setprio(0);

      // rel-shift via Bds (stride 94, +4*lg skew: write & read both clean 2-way)
#pragma unroll
      for (int pt = 0; pt < 5; ++pt)
#pragma unroll
        for (int q = 0; q < 4; ++q)
          wb[(lg * 4 + q) * 94 + pt * 16 + lr + lg * 4] = cP5[pt][q];
      float sv[4][4];
#pragma unroll
      for (int nt = 0; nt < 4; ++nt)
#pragma unroll
        for (int q = 0; q < 4; ++q)
          sv[nt][q] = 0.125f * (cK[f][nt][q] +
                                wb[(lg * 4 + q) * 94 + 15 - q + nt * 16 + lr]);

      // online softmax with defer-max (THR=8)
      float pm[4];
#pragma unroll
      for (int q = 0; q < 4; ++q) {
        float tm = fmaxf(fmaxf(sv[0][q], sv[1][q]), fmaxf(sv[2][q], sv[3][q]));
        DPPMAX(tm, 0xB1);
        DPPMAX(tm, 0x4E);
        DPPMAX(tm, 0x141);
        DPPMAX(tm, 0x140);
        pm[q] = tm;
      }
      int need = 0;
#pragma unroll
      for (int q = 0; q < 4; ++q) need |= (pm[q] > mrun[f][q] + 8.f) ? 1 : 0;
      if (__any(need)) {
#pragma unroll
        for (int q = 0; q < 4; ++q) {
          float mnew = fmaxf(mrun[f][q], pm[q]);
          float corr = __expf(mrun[f][q] - mnew);
          mrun[f][q] = mnew;
          cL[f][q] *= corr;
#pragma unroll
          for (int nt = 0; nt < 4; ++nt) cO[f][nt][q] *= corr;
        }
      }

      // exp -> bf16 -> Es (overlaid on Bds region; Bds fully read above)
#pragma unroll
      for (int nt = 0; nt < 4; ++nt) {
        int jp = nt * 16 + lr, sw = jp >> 3, jb8 = jp & 7;
#pragma unroll
        for (int q = 0; q < 4; ++q) {
          int m = lg * 4 + q;
          esw[m * 64 + ((sw ^ (m & 7)) * 8) + jb8] = f2bf(__expf(sv[nt][q] - mrun[f][q]));
        }
      }

      // PV + denominator
      __builtin_amdgcn_s_setprio(1);
#pragma unroll
      for (int kc = 0; kc < 2; ++kc) {
        const int ch = kc * 4 + lg;
        short8 ae = *(const short8*)&esw[lr * 64 + ((ch ^ (lr & 7)) * 8)];
        cL[f] = __builtin_amdgcn_mfma_f32_16x16x32_bf16(ae, ones, cL[f], 0, 0, 0);
#pragma unroll
        for (int nt = 0; nt < 4; ++nt) {
          int vr = nt * 16 + lr;
          short8 bv = *(const short8*)&Vs[grp][vr * 64 + ((ch ^ (vr & 7)) * 8)];
          cO[f][nt] = __builtin_amdgcn_mfma_f32_16x16x32_bf16(ae, bv, cO[f][nt], 0, 0, 0);
        }
      }
      __builtin_amdgcn_s_setprio(0);
    }

    __syncthreads();
    // ---- write staged tiles for next superstep ----
    if (s < 7) {
#pragma unroll
      for (int r = 0; r < 4; ++r) {
        int idx = tid + 256 * r;
        int row = idx >> 3, sc = idx & 7;
        *(short8*)&Ks[row >> 6][(row & 63) * 64 + ((sc ^ (row & 7)) * 8)] = nk[r];
        *(short8*)&Vs[row >> 6][(row & 63) * 64 + ((sc ^ (row & 7)) * 8)] = nv[r];
        int pph = jbs + row;
        if (pph >= 192) pph -= 192;
        *(short8*)&Ps[pph * 64 + ((sc ^ (row & 7)) * 8)] = np[r];
      }
    }
    jbs += 128; if (jbs >= 192) jbs -= 192;
    jb_self += 128; if (jb_self >= 192) jb_self -= 192;
    __syncthreads();
  }

  // ---- merge j-halves (exact flash merge) ----
  float* ob = (float*)&Ks[0][0];   // 64 rows x 64 cols f32 = 16 KB
  float* mlb = (float*)&Vs[0][0];  // 64 rows x {m,l}
  if (grp == 1) {
#pragma unroll
    for (int f = 0; f < 2; ++f)
#pragma unroll
      for (int nt = 0; nt < 4; ++nt)
#pragma unroll
        for (int q = 0; q < 4; ++q)
          ob[(wq * 32 + 16 * f + 4 * lg + q) * 64 + nt * 16 + lr] = cO[f][nt][q];
    if (lr == 0) {
#pragma unroll
      for (int f = 0; f < 2; ++f)
#pragma unroll
        for (int q = 0; q < 4; ++q) {
          int rr = wq * 32 + 16 * f + 4 * lg + q;
          mlb[rr * 2 + 0] = mrun[f][q];
          mlb[rr * 2 + 1] = cL[f][q];
        }
    }
  }
  __syncthreads();
  if (grp == 0) {
#pragma unroll
    for (int f = 0; f < 2; ++f) {
      float ws0[4], ws1[4];
#pragma unroll
      for (int q = 0; q < 4; ++q) {
        int rr = wq * 32 + 16 * f + 4 * lg + q;
        float m1 = mlb[rr * 2 + 0], l1 = mlb[rr * 2 + 1];
        float M = fmaxf(mrun[f][q], m1);
        float w0 = __expf(mrun[f][q] - M), w1 = __expf(m1 - M);
        float inv = 1.f / (w0 * cL[f][q] + w1 * l1);
        ws0[q] = w0 * inv;
        ws1[q] = w1 * inv;
      }
#pragma unroll
      for (int nt = 0; nt < 4; ++nt)
#pragma unroll
        for (int q = 0; q < 4; ++q) {
          int rr = wq * 32 + 16 * f + 4 * lg + q;
          float o1 = ob[rr * 64 + nt * 16 + lr];
          float val = ws0[q] * cO[f][nt][q] + ws1[q] * o1;
          ao[(size_t)(b * SEQ + t0 + rr) * 512 + h * 64 + nt * 16 + lr] = f2bf(val);
        }
    }
  }
}

extern "C" void kernel_launch(void* const* d_in, const int* in_sizes, int n_in,
                              void* d_out, int out_size, void* d_ws, size_t ws_size,
                              hipStream_t stream) {
  const float* x   = (const float*)d_in[0];
  const float* pe  = (const float*)d_in[1];
  const float* Wq  = (const float*)d_in[2];
  const float* bq  = (const float*)d_in[3];
  const float* Wk  = (const float*)d_in[4];
  const float* bk  = (const float*)d_in[5];
  const float* Wv  = (const float*)d_in[6];
  const float* bv  = (const float*)d_in[7];
  const float* Wp  = (const float*)d_in[8];
  const float* bp  = (const float*)d_in[9];
  const float* Wo  = (const float*)d_in[10];
  const float* bo  = (const float*)d_in[11];
  const float* pbu = (const float*)d_in[12];
  const float* pbv = (const float*)d_in[13];

  char* ws = (char*)d_ws;
  size_t o = 0;
  auto alloc = [&](size_t bytes) { size_t r = o; o += (bytes + 255) & ~(size_t)255; return r; };
  u16* x_bf  = (u16*)(ws + alloc((size_t)4096 * 512 * 2));
  u16* pe_bf = (u16*)(ws + alloc((size_t)2048 * 512 * 2));
  u16* wt    = (u16*)(ws + alloc((size_t)5 * 512 * 512 * 2));
  u16* qu    = (u16*)(ws + alloc((size_t)4096 * 512 * 2));
  u16* qv    = (u16*)(ws + alloc((size_t)4096 * 512 * 2));
  u16* kk    = (u16*)(ws + alloc((size_t)4096 * 512 * 2));
  u16* vt    = (u16*)(ws + alloc((size_t)4096 * 512 * 2));
  u16* pp    = (u16*)(ws + alloc((size_t)2048 * 512 * 2));
  u16* ao    = (u16*)(ws + alloc((size_t)4096 * 512 * 2));

  dim3 blk(256);
  cvt_two<<<dim3(3072), blk, 0, stream>>>(x, pe, x_bf, pe_bf);
  transpose_w<<<dim3(16, 16, 5), dim3(32, 8), 0, stream>>>(Wq, Wk, Wv, Wp, Wo, wt);
  hipMemsetAsync(pp + (size_t)2047 * 512, 0, 512 * 2, stream);

  gemm_qkvp<<<dim3(4, 32, 4), blk, 0, stream>>>(x_bf, pe_bf, wt, bq, bk, bv, bp,
                                                pbu, pbv, qu, qv, kk, vt, pp);
  attn_mfma<<<dim3(16, NHEAD, BATCH), blk, 0, stream>>>(qu, qv, kk, vt, pp, ao);
  gemm_wo<<<dim3(8, 64), blk, 0, stream>>>(ao, wt, bo, (float*)d_out);
}

// Round 8
// 82.783 us; speedup vs baseline: 1.3291x; 1.3291x over previous
//
#include <hip/hip_runtime.h>
#include <math.h>

#define BATCH 4
#define SEQ   1024
#define HID   512
#define NHEAD 8

typedef unsigned short u16;
typedef unsigned int   u32;
typedef short  short8 __attribute__((ext_vector_type(8)));
typedef float  f32x4  __attribute__((ext_vector_type(4)));

__device__ __forceinline__ u16 f2bf(float x) {
  u32 u = __builtin_bit_cast(u32, x);
  u32 r = (u + 0x7FFFu + ((u >> 16) & 1u)) >> 16;
  return (u16)r;
}

// max-reduce over the 16 lanes of a row via DPP (VALU only, no DS ops)
#define DPPMAX(x, ctrl)                                                        \
  x = fmaxf(x, __builtin_bit_cast(float, __builtin_amdgcn_update_dpp(          \
                   0, __builtin_bit_cast(int, x), ctrl, 0xf, 0xf, true)))

// ---------------- fp32 -> bf16 convert: x (524288 float4s) then pe (262016) --
__global__ __launch_bounds__(256)
void cvt_two(const float* __restrict__ x, const float* __restrict__ pe,
             u16* __restrict__ xb, u16* __restrict__ peb) {
  int i = blockIdx.x * 256 + threadIdx.x;
  const float* s;
  u16* d;
  if (i < 524288) {
    s = x; d = xb;
  } else {
    i -= 524288;
    if (i >= 262016) return;
    s = pe; d = peb;
  }
  float4 v = *(const float4*)&s[(size_t)i * 4];
  ushort4 o;
  o.x = f2bf(v.x); o.y = f2bf(v.y); o.z = f2bf(v.z); o.w = f2bf(v.w);
  *(ushort4*)&d[(size_t)i * 4] = o;
}

// ---------------- W (512x512 f32 k-major) -> Wt (n-major bf16), 5 mats -------
__global__ __launch_bounds__(256)
void transpose_w(const float* w0, const float* w1, const float* w2,
                 const float* w3, const float* w4, u16* __restrict__ wt) {
  const float* src;
  switch (blockIdx.z) {
    case 0: src = w0; break;
    case 1: src = w1; break;
    case 2: src = w2; break;
    case 3: src = w3; break;
    default: src = w4; break;
  }
  u16* dst = wt + (size_t)blockIdx.z * 512 * 512;
  __shared__ float t[32][33];
  const int tx = threadIdx.x, ty = threadIdx.y;  // block (32,8)
  const int k0 = blockIdx.x * 32, n0 = blockIdx.y * 32;
#pragma unroll
  for (int r = 0; r < 4; ++r)
    t[ty + 8 * r][tx] = src[(size_t)(k0 + ty + 8 * r) * 512 + n0 + tx];
  __syncthreads();
#pragma unroll
  for (int r = 0; r < 4; ++r)
    dst[(size_t)(n0 + ty + 8 * r) * 512 + k0 + tx] = f2bf(t[tx][ty + 8 * r]);
}

// ---------------- MFMA GEMM core: acc = A[BMx512] @ Bt^T tile ---------------
template <int MF, int NF>
__device__ __forceinline__ void gemm_core(const u16* __restrict__ A,
                                          const u16* __restrict__ Bt,
                                          int m0, int n0, u16* As, u16* Bs,
                                          f32x4 (&acc)[MF][NF]) {
  const int tid = threadIdx.x;
  const int wid = tid >> 6, lane = tid & 63;
  const int lr = lane & 15, lg = lane >> 4;
  const int wm = wid >> 1, wn = wid & 1;
  const int srow = tid >> 3, sc = tid & 7;
#pragma unroll
  for (int i = 0; i < MF; ++i)
#pragma unroll
    for (int j = 0; j < NF; ++j) acc[i][j] = (f32x4)0.f;

  for (int kt = 0; kt < 8; ++kt) {
    const int k0 = kt * 64;
    short8 la[MF], lb[NF];
#pragma unroll
    for (int r = 0; r < MF; ++r)
      la[r] = *(const short8*)&A[(size_t)(m0 + srow + 32 * r) * 512 + k0 + sc * 8];
#pragma unroll
    for (int r = 0; r < NF; ++r)
      lb[r] = *(const short8*)&Bt[(size_t)(n0 + srow + 32 * r) * 512 + k0 + sc * 8];
    __syncthreads();
#pragma unroll
    for (int r = 0; r < MF; ++r) {
      int row = srow + 32 * r;
      *(short8*)&As[row * 64 + ((sc ^ (row & 7)) * 8)] = la[r];
    }
#pragma unroll
    for (int r = 0; r < NF; ++r) {
      int row = srow + 32 * r;
      *(short8*)&Bs[row * 64 + ((sc ^ (row & 7)) * 8)] = lb[r];
    }
    __syncthreads();
#pragma unroll
    for (int kc = 0; kc < 2; ++kc) {
      const int ch = kc * 4 + lg;
      short8 af[MF], bfr[NF];
#pragma unroll
      for (int mt = 0; mt < MF; ++mt) {
        int row = wm * (MF * 16) + mt * 16 + lr;
        af[mt] = *(const short8*)&As[row * 64 + ((ch ^ (row & 7)) * 8)];
      }
#pragma unroll
      for (int nt = 0; nt < NF; ++nt) {
        int row = wn * (NF * 16) + nt * 16 + lr;
        bfr[nt] = *(const short8*)&Bs[row * 64 + ((ch ^ (row & 7)) * 8)];
      }
#pragma unroll
      for (int mt = 0; mt < MF; ++mt)
#pragma unroll
        for (int nt = 0; nt < NF; ++nt)
          acc[mt][nt] = __builtin_amdgcn_mfma_f32_16x16x32_bf16(
              af[mt], bfr[nt], acc[mt][nt], 0, 0, 0);
    }
  }
}

// ---------------- fused Q/K/V/P projection GEMM (z = 0..3) ------------------
__global__ __launch_bounds__(256)
void gemm_qkvp(const u16* __restrict__ xbf, const u16* __restrict__ pebf,
               const u16* __restrict__ wt,
               const float* __restrict__ bq, const float* __restrict__ bk,
               const float* __restrict__ bv, const float* __restrict__ bp,
               const float* __restrict__ pbu, const float* __restrict__ pbv,
               u16* __restrict__ qu, u16* __restrict__ qv,
               u16* __restrict__ kk, u16* __restrict__ vt,
               u16* __restrict__ pp) {
  __shared__ __align__(16) u16 As[128 * 64];
  __shared__ __align__(16) u16 Bs[128 * 64];
  const int z = blockIdx.z;
  if (z == 3 && blockIdx.y >= 16) return;
  const u16* A = (z == 3) ? pebf : xbf;
  const u16* Bt = wt + (size_t)z * 512 * 512;
  const float* bias = (z == 0) ? bq : (z == 1) ? bk : (z == 2) ? bv : bp;
  const int m0 = blockIdx.y * 128, n0 = blockIdx.x * 128;

  f32x4 acc[4][4];
  gemm_core<4, 4>(A, Bt, m0, n0, As, Bs, acc);

  const int tid = threadIdx.x, wid = tid >> 6, lane = tid & 63;
  const int lr = lane & 15, lg = lane >> 4, wm = wid >> 1, wn = wid & 1;
#pragma unroll
  for (int mt = 0; mt < 4; ++mt)
#pragma unroll
    for (int nt = 0; nt < 4; ++nt) {
      const int col = n0 + wn * 64 + nt * 16 + lr;
      const int rb = m0 + wm * 64 + mt * 16 + lg * 4;
      const float bcol = bias[col];
      if (z == 0) {
        const float uu = pbu[col], vv = pbv[col];
#pragma unroll
        for (int q = 0; q < 4; ++q) {
          float val = acc[mt][nt][q] + bcol;
          qu[(size_t)(rb + q) * 512 + col] = f2bf(val + uu);
          qv[(size_t)(rb + q) * 512 + col] = f2bf(val + vv);
        }
      } else if (z == 1) {
#pragma unroll
        for (int q = 0; q < 4; ++q)
          kk[(size_t)(rb + q) * 512 + col] = f2bf(acc[mt][nt][q] + bcol);
      } else if (z == 2) {
        // V^T layout [b][h][d][t]
        ushort4 pk;
        pk.x = f2bf(acc[mt][nt][0] + bcol);
        pk.y = f2bf(acc[mt][nt][1] + bcol);
        pk.z = f2bf(acc[mt][nt][2] + bcol);
        pk.w = f2bf(acc[mt][nt][3] + bcol);
        int bb = rb >> 10, tl = rb & 1023;
        *(ushort4*)&vt[(size_t)((bb * 8 + (col >> 6)) * 64 + (col & 63)) * 1024 + tl] = pk;
      } else {
#pragma unroll
        for (int q = 0; q < 4; ++q)
          if (rb + q < 2047)
            pp[(size_t)(rb + q) * 512 + col] = f2bf(acc[mt][nt][q] + bcol);
      }
    }
}

// ---------------- output projection: out = ao @ Wo^T + bo (f32) -------------
__global__ __launch_bounds__(256)
void gemm_wo(const u16* __restrict__ ao, const u16* __restrict__ wt,
             const float* __restrict__ bo, float* __restrict__ out) {
  __shared__ __align__(16) u16 As[64 * 64];
  __shared__ __align__(16) u16 Bs[64 * 64];
  const int m0 = blockIdx.y * 64, n0 = blockIdx.x * 64;
  f32x4 acc[2][2];
  gemm_core<2, 2>(ao, wt + (size_t)4 * 512 * 512, m0, n0, As, Bs, acc);
  const int tid = threadIdx.x, wid = tid >> 6, lane = tid & 63;
  const int lr = lane & 15, lg = lane >> 4, wm = wid >> 1, wn = wid & 1;
#pragma unroll
  for (int mt = 0; mt < 2; ++mt)
#pragma unroll
    for (int nt = 0; nt < 2; ++nt) {
      const int col = n0 + wn * 32 + nt * 16 + lr;
      const int rb = m0 + wm * 32 + mt * 16 + lg * 4;
      const float bcol = bo[col];
#pragma unroll
      for (int q = 0; q < 4; ++q)
        out[(size_t)(rb + q) * 512 + col] = acc[mt][nt][q] + bcol;
    }
}

// ---------------- flash rel-pos attention, bf16 MFMA ------------------------
// Block: 512 thr = 8 waves, 128 q-rows. Wave (grp = wid>>2, wq = wid&3):
// grp 0 -> even 64-col j-tiles, grp 1 -> odd; wq selects 32 rows (2 frags f).
// K/V frag reads feed 2 MFMAs (f=0,1); V frags hoisted to regs across f.
// P held in a 256-row ring (mod = &255). End merge of j-halves in LDS.
__global__ __launch_bounds__(512)
void attn_mfma(const u16* __restrict__ quP, const u16* __restrict__ qvP,
               const u16* __restrict__ kP, const u16* __restrict__ vtP,
               const u16* __restrict__ pP, u16* __restrict__ ao) {
  // layout (u16 units): Ks[2] @0 (8KB), Vs[2] @8192 (16KB tot 32KB w/ Ks),
  // Ps @16384 (32KB), Wb @32768 (48KB f32)
  __shared__ __align__(16) u16 SM[56832];
  u16* Ps = SM + 16384;

  const int tid = threadIdx.x;
  const int wid = tid >> 6, lane = tid & 63;
  const int lr = lane & 15, lg = lane >> 4;
  const int grp = wid >> 2, wq = wid & 3;
  const int t0 = blockIdx.x * 128, h = blockIdx.y, b = blockIdx.z;
  const int base0 = 896 - t0;  // P ring pos 0 <-> rel index base0

  u16* Ksg = SM + grp * 4096;
  u16* Vsg = SM + 8192 + grp * 4096;
  float* wb = (float*)(SM + 32768) + wid * 1504;
  u16* esw = (u16*)wb;

  // Q fragments: frag f covers rows t0 + 32*wq + 16*f .. +15
  short8 aqu[2][2], aqv[2][2];
#pragma unroll
  for (int f = 0; f < 2; ++f)
#pragma unroll
    for (int kc = 0; kc < 2; ++kc) {
      size_t g = (size_t)(b * SEQ + t0 + 32 * wq + 16 * f + lr) * 512 + h * 64 +
                 kc * 32 + lg * 8;
      aqu[f][kc] = *(const short8*)&quP[g];
      aqv[f][kc] = *(const short8*)&qvP[g];
    }
  short8 ones;
#pragma unroll
  for (int i = 0; i < 8; ++i) ones[i] = (short)0x3F80;  // bf16 1.0

  float mrun[2][4];
  f32x4 cL[2], cO[2][4];
#pragma unroll
  for (int f = 0; f < 2; ++f) {
    cL[f] = (f32x4)0.f;
#pragma unroll
    for (int q = 0; q < 4; ++q) mrun[f][q] = -1e30f;
#pragma unroll
    for (int nt = 0; nt < 4; ++nt) cO[f][nt] = (f32x4)0.f;
  }

  // ---- prologue staging: K/V j-rows 0..127, P ring rel base0..base0+255 ----
#pragma unroll
  for (int r = 0; r < 2; ++r) {
    int idx = tid + 512 * r;
    int row = idx >> 3, sc = idx & 7;
    short8 lk = *(const short8*)&kP[(size_t)(b * SEQ + row) * 512 + h * 64 + sc * 8];
    short8 lv = *(const short8*)&vtP[(size_t)((b * 8 + h) * 64 + (row & 63)) * 1024 +
                                     (row >> 6) * 64 + sc * 8];
    *(short8*)&SM[(row >> 6) * 4096 + (row & 63) * 64 + ((sc ^ (row & 7)) * 8)] = lk;
    *(short8*)&SM[8192 + (row >> 6) * 4096 + (row & 63) * 64 + ((sc ^ (row & 7)) * 8)] = lv;
  }
#pragma unroll
  for (int r = 0; r < 4; ++r) {
    int idx = tid + 512 * r;
    int prow = idx >> 3, sc = idx & 7;  // 0..255
    short8 lp = *(const short8*)&pP[(size_t)(base0 + prow) * 512 + h * 64 + sc * 8];
    *(short8*)&Ps[prow * 64 + ((sc ^ (prow & 7)) * 8)] = lp;
  }
  __syncthreads();

  for (int s = 0; s < 8; ++s) {
    // ---- T14: issue next superstep's global loads early ----
    short8 nk[2], nv[2], np[2];
    if (s < 7) {
      const int jn = 128 * (s + 1);
#pragma unroll
      for (int r = 0; r < 2; ++r) {
        int idx = tid + 512 * r;
        int row = idx >> 3, sc = idx & 7;
        nk[r] = *(const short8*)&kP[(size_t)(b * SEQ + jn + row) * 512 + h * 64 + sc * 8];
        nv[r] = *(const short8*)&vtP[(size_t)((b * 8 + h) * 64 + (row & 63)) * 1024 +
                                     jn + (row >> 6) * 64 + sc * 8];
        np[r] = *(const short8*)&pP[(size_t)(base0 + 256 + 128 * s + row) * 512 +
                                    h * 64 + sc * 8];
      }
    }

    // ---- K-score MFMAs: both row-frags share each K fragment ----
    f32x4 cK[2][4];
#pragma unroll
    for (int f = 0; f < 2; ++f)
#pragma unroll
      for (int nt = 0; nt < 4; ++nt) cK[f][nt] = (f32x4)0.f;
    __builtin_amdgcn_s_setprio(1);
#pragma unroll
    for (int kc = 0; kc < 2; ++kc) {
      const int ch = kc * 4 + lg;
#pragma unroll
      for (int nt = 0; nt < 4; ++nt) {
        int krow = nt * 16 + lr;
        short8 bk = *(const short8*)&Ksg[krow * 64 + ((ch ^ (krow & 7)) * 8)];
        cK[0][nt] = __builtin_amdgcn_mfma_f32_16x16x32_bf16(aqu[0][kc], bk, cK[0][nt], 0, 0, 0);
        cK[1][nt] = __builtin_amdgcn_mfma_f32_16x16x32_bf16(aqu[1][kc], bk, cK[1][nt], 0, 0, 0);
      }
    }
    __builtin_amdgcn_s_setprio(0);

    // ---- hoist V fragments (each feeds both f's PV) ----
    short8 bvr[2][4];
#pragma unroll
    for (int kc = 0; kc < 2; ++kc) {
      const int ch = kc * 4 + lg;
#pragma unroll
      for (int nt = 0; nt < 4; ++nt) {
        int vr = nt * 16 + lr;
        bvr[kc][nt] = *(const short8*)&Vsg[vr * 64 + ((ch ^ (vr & 7)) * 8)];
      }
    }

#pragma unroll
    for (int f = 0; f < 2; ++f) {
      // window position offset (>= 0): ring pos = (poff + pt*16 + lr) & 255
      const int poff = 112 - 32 * wq - 16 * f + 64 * grp + 128 * s;
      f32x4 cP5[5];
#pragma unroll
      for (int i = 0; i < 5; ++i) cP5[i] = (f32x4)0.f;
      __builtin_amdgcn_s_setprio(1);
#pragma unroll
      for (int kc = 0; kc < 2; ++kc) {
        const int ch = kc * 4 + lg;
        const int swz = (ch ^ (lr & 7)) * 8;  // pos & 7 == lr & 7
#pragma unroll
        for (int pt = 0; pt < 5; ++pt) {
          int pos = (poff + pt * 16 + lr) & 255;
          short8 bp = *(const short8*)&Ps[pos * 64 + swz];
          cP5[pt] = __builtin_amdgcn_mfma_f32_16x16x32_bf16(aqv[f][kc], bp, cP5[pt], 0, 0, 0);
        }
      }
      __builtin_amdgcn_s_setprio(0);

      // rel-shift via per-wave LDS round-trip (stride 94, +4*lg skew)
#pragma unroll
      for (int pt = 0; pt < 5; ++pt)
#pragma unroll
        for (int q = 0; q < 4; ++q)
          wb[(lg * 4 + q) * 94 + pt * 16 + lr + lg * 4] = cP5[pt][q];
      float sv[4][4];
#pragma unroll
      for (int nt = 0; nt < 4; ++nt)
#pragma unroll
        for (int q = 0; q < 4; ++q)
          sv[nt][q] = 0.125f * (cK[f][nt][q] +
                                wb[(lg * 4 + q) * 94 + 15 - q + nt * 16 + lr]);

      // online softmax with defer-max (THR=8)
      float pm[4];
#pragma unroll
      for (int q = 0; q < 4; ++q) {
        float tm = fmaxf(fmaxf(sv[0][q], sv[1][q]), fmaxf(sv[2][q], sv[3][q]));
        DPPMAX(tm, 0xB1);
        DPPMAX(tm, 0x4E);
        DPPMAX(tm, 0x141);
        DPPMAX(tm, 0x140);
        pm[q] = tm;
      }
      int need = 0;
#pragma unroll
      for (int q = 0; q < 4; ++q) need |= (pm[q] > mrun[f][q] + 8.f) ? 1 : 0;
      if (__any(need)) {
#pragma unroll
        for (int q = 0; q < 4; ++q) {
          float mnew = fmaxf(mrun[f][q], pm[q]);
          float corr = __expf(mrun[f][q] - mnew);
          mrun[f][q] = mnew;
          cL[f][q] *= corr;
#pragma unroll
          for (int nt = 0; nt < 4; ++nt) cO[f][nt][q] *= corr;
        }
      }

      // exp -> bf16 -> Es (overlaid on Bds; Bds fully consumed above)
#pragma unroll
      for (int nt = 0; nt < 4; ++nt) {
        int jp = nt * 16 + lr, sw = jp >> 3, jb8 = jp & 7;
#pragma unroll
        for (int q = 0; q < 4; ++q) {
          int m = lg * 4 + q;
          esw[m * 64 + ((sw ^ (m & 7)) * 8) + jb8] = f2bf(__expf(sv[nt][q] - mrun[f][q]));
        }
      }

      // PV + denominator (V frags from registers)
      __builtin_amdgcn_s_setprio(1);
#pragma unroll
      for (int kc = 0; kc < 2; ++kc) {
        const int ch = kc * 4 + lg;
        short8 ae = *(const short8*)&esw[lr * 64 + ((ch ^ (lr & 7)) * 8)];
        cL[f] = __builtin_amdgcn_mfma_f32_16x16x32_bf16(ae, ones, cL[f], 0, 0, 0);
#pragma unroll
        for (int nt = 0; nt < 4; ++nt)
          cO[f][nt] = __builtin_amdgcn_mfma_f32_16x16x32_bf16(ae, bvr[kc][nt], cO[f][nt], 0, 0, 0);
      }
      __builtin_amdgcn_s_setprio(0);
    }

    __syncthreads();
    // ---- write staged tiles for next superstep ----
    if (s < 7) {
#pragma unroll
      for (int r = 0; r < 2; ++r) {
        int idx = tid + 512 * r;
        int row = idx >> 3, sc = idx & 7;
        *(short8*)&SM[(row >> 6) * 4096 + (row & 63) * 64 + ((sc ^ (row & 7)) * 8)] = nk[r];
        *(short8*)&SM[8192 + (row >> 6) * 4096 + (row & 63) * 64 + ((sc ^ (row & 7)) * 8)] = nv[r];
        int pos = (128 * s + row) & 255;  // == (256 + 128s + row) mod 256
        *(short8*)&Ps[pos * 64 + ((sc ^ (pos & 7)) * 8)] = np[r];
      }
    }
    __syncthreads();
  }

  // ---- merge j-halves (exact flash merge) via LDS overlay ----
  float* ob = (float*)SM;           // 128 x 64 f32 = 32KB (Ks+Vs region)
  float* mlb = (float*)(SM + 16384);  // 128 x {m,l} (Ps region)
  if (grp == 1) {
#pragma unroll
    for (int f = 0; f < 2; ++f) {
#pragma unroll
      for (int nt = 0; nt < 4; ++nt)
#pragma unroll
        for (int q = 0; q < 4; ++q)
          ob[(wq * 32 + 16 * f + 4 * lg + q) * 64 + nt * 16 + lr] = cO[f][nt][q];
      if (lr == 0) {
#pragma unroll
        for (int q = 0; q < 4; ++q) {
          int rr = wq * 32 + 16 * f + 4 * lg + q;
          mlb[rr * 2 + 0] = mrun[f][q];
          mlb[rr * 2 + 1] = cL[f][q];
        }
      }
    }
  }
  __syncthreads();
  if (grp == 0) {
#pragma unroll
    for (int f = 0; f < 2; ++f) {
      float ws0[4], ws1[4];
#pragma unroll
      for (int q = 0; q < 4; ++q) {
        int rr = wq * 32 + 16 * f + 4 * lg + q;
        float m1 = mlb[rr * 2 + 0], l1 = mlb[rr * 2 + 1];
        float M = fmaxf(mrun[f][q], m1);
        float w0 = __expf(mrun[f][q] - M), w1 = __expf(m1 - M);
        float inv = 1.f / (w0 * cL[f][q] + w1 * l1);
        ws0[q] = w0 * inv;
        ws1[q] = w1 * inv;
      }
#pragma unroll
      for (int nt = 0; nt < 4; ++nt)
#pragma unroll
        for (int q = 0; q < 4; ++q) {
          int rr = wq * 32 + 16 * f + 4 * lg + q;
          float o1 = ob[rr * 64 + nt * 16 + lr];
          float val = ws0[q] * cO[f][nt][q] + ws1[q] * o1;
          ao[(size_t)(b * SEQ + t0 + rr) * 512 + h * 64 + nt * 16 + lr] = f2bf(val);
        }
    }
  }
}

extern "C" void kernel_launch(void* const* d_in, const int* in_sizes, int n_in,
                              void* d_out, int out_size, void* d_ws, size_t ws_size,
                              hipStream_t stream) {
  const float* x   = (const float*)d_in[0];
  const float* pe  = (const float*)d_in[1];
  const float* Wq  = (const float*)d_in[2];
  const float* bq  = (const float*)d_in[3];
  const float* Wk  = (const float*)d_in[4];
  const float* bk  = (const float*)d_in[5];
  const float* Wv  = (const float*)d_in[6];
  const float* bv  = (const float*)d_in[7];
  const float* Wp  = (const float*)d_in[8];
  const float* bp  = (const float*)d_in[9];
  const float* Wo  = (const float*)d_in[10];
  const float* bo  = (const float*)d_in[11];
  const float* pbu = (const float*)d_in[12];
  const float* pbv = (const float*)d_in[13];

  char* ws = (char*)d_ws;
  size_t o = 0;
  auto alloc = [&](size_t bytes) { size_t r = o; o += (bytes + 255) & ~(size_t)255; return r; };
  u16* x_bf  = (u16*)(ws + alloc((size_t)4096 * 512 * 2));
  u16* pe_bf = (u16*)(ws + alloc((size_t)2048 * 512 * 2));
  u16* wt    = (u16*)(ws + alloc((size_t)5 * 512 * 512 * 2));
  u16* qu    = (u16*)(ws + alloc((size_t)4096 * 512 * 2));
  u16* qv    = (u16*)(ws + alloc((size_t)4096 * 512 * 2));
  u16* kk    = (u16*)(ws + alloc((size_t)4096 * 512 * 2));
  u16* vt    = (u16*)(ws + alloc((size_t)4096 * 512 * 2));
  u16* pp    = (u16*)(ws + alloc((size_t)2048 * 512 * 2));
  u16* ao    = (u16*)(ws + alloc((size_t)4096 * 512 * 2));

  dim3 blk(256);
  cvt_two<<<dim3(3072), blk, 0, stream>>>(x, pe, x_bf, pe_bf);
  transpose_w<<<dim3(16, 16, 5), dim3(32, 8), 0, stream>>>(Wq, Wk, Wv, Wp, Wo, wt);
  hipMemsetAsync(pp + (size_t)2047 * 512, 0, 512 * 2, stream);

  gemm_qkvp<<<dim3(4, 32, 4), blk, 0, stream>>>(x_bf, pe_bf, wt, bq, bk, bv, bp,
                                                pbu, pbv, qu, qv, kk, vt, pp);
  attn_mfma<<<dim3(8, NHEAD, BATCH), dim3(512), 0, stream>>>(qu, qv, kk, vt, pp, ao);
  gemm_wo<<<dim3(8, 64), blk, 0, stream>>>(ao, wt, bo, (float*)d_out);
}

// Round 9
// 76.455 us; speedup vs baseline: 1.4391x; 1.0828x over previous
//
#include <hip/hip_runtime.h>
#include <math.h>

#define BATCH 4
#define SEQ   1024
#define HID   512
#define NHEAD 8

typedef unsigned short u16;
typedef unsigned int   u32;
typedef short  short8 __attribute__((ext_vector_type(8)));
typedef float  f32x4  __attribute__((ext_vector_type(4)));

__device__ __forceinline__ u16 f2bf(float x) {
  u32 u = __builtin_bit_cast(u32, x);
  u32 r = (u + 0x7FFFu + ((u >> 16) & 1u)) >> 16;
  return (u16)r;
}

// ---------------- fp32 -> bf16 convert: x (524288 float4s) then pe (262016) --
__global__ __launch_bounds__(256)
void cvt_two(const float* __restrict__ x, const float* __restrict__ pe,
             u16* __restrict__ xb, u16* __restrict__ peb) {
  int i = blockIdx.x * 256 + threadIdx.x;
  const float* s;
  u16* d;
  if (i < 524288) {
    s = x; d = xb;
  } else {
    i -= 524288;
    if (i >= 262016) return;
    s = pe; d = peb;
  }
  float4 v = *(const float4*)&s[(size_t)i * 4];
  ushort4 o;
  o.x = f2bf(v.x); o.y = f2bf(v.y); o.z = f2bf(v.z); o.w = f2bf(v.w);
  *(ushort4*)&d[(size_t)i * 4] = o;
}

// ---------------- W (512x512 f32 k-major) -> Wt (n-major bf16), 5 mats -------
__global__ __launch_bounds__(256)
void transpose_w(const float* w0, const float* w1, const float* w2,
                 const float* w3, const float* w4, u16* __restrict__ wt) {
  const float* src;
  switch (blockIdx.z) {
    case 0: src = w0; break;
    case 1: src = w1; break;
    case 2: src = w2; break;
    case 3: src = w3; break;
    default: src = w4; break;
  }
  u16* dst = wt + (size_t)blockIdx.z * 512 * 512;
  __shared__ float t[32][33];
  const int tx = threadIdx.x, ty = threadIdx.y;  // block (32,8)
  const int k0 = blockIdx.x * 32, n0 = blockIdx.y * 32;
#pragma unroll
  for (int r = 0; r < 4; ++r)
    t[ty + 8 * r][tx] = src[(size_t)(k0 + ty + 8 * r) * 512 + n0 + tx];
  __syncthreads();
#pragma unroll
  for (int r = 0; r < 4; ++r)
    dst[(size_t)(n0 + ty + 8 * r) * 512 + k0 + tx] = f2bf(t[tx][ty + 8 * r]);
}

// ---------------- MFMA GEMM core: acc = A[BMx512] @ Bt^T tile ---------------
template <int MF, int NF>
__device__ __forceinline__ void gemm_core(const u16* __restrict__ A,
                                          const u16* __restrict__ Bt,
                                          int m0, int n0, u16* As, u16* Bs,
                                          f32x4 (&acc)[MF][NF]) {
  const int tid = threadIdx.x;
  const int wid = tid >> 6, lane = tid & 63;
  const int lr = lane & 15, lg = lane >> 4;
  const int wm = wid >> 1, wn = wid & 1;
  const int srow = tid >> 3, sc = tid & 7;
#pragma unroll
  for (int i = 0; i < MF; ++i)
#pragma unroll
    for (int j = 0; j < NF; ++j) acc[i][j] = (f32x4)0.f;

  for (int kt = 0; kt < 8; ++kt) {
    const int k0 = kt * 64;
    short8 la[MF], lb[NF];
#pragma unroll
    for (int r = 0; r < MF; ++r)
      la[r] = *(const short8*)&A[(size_t)(m0 + srow + 32 * r) * 512 + k0 + sc * 8];
#pragma unroll
    for (int r = 0; r < NF; ++r)
      lb[r] = *(const short8*)&Bt[(size_t)(n0 + srow + 32 * r) * 512 + k0 + sc * 8];
    __syncthreads();
#pragma unroll
    for (int r = 0; r < MF; ++r) {
      int row = srow + 32 * r;
      *(short8*)&As[row * 64 + ((sc ^ (row & 7)) * 8)] = la[r];
    }
#pragma unroll
    for (int r = 0; r < NF; ++r) {
      int row = srow + 32 * r;
      *(short8*)&Bs[row * 64 + ((sc ^ (row & 7)) * 8)] = lb[r];
    }
    __syncthreads();
#pragma unroll
    for (int kc = 0; kc < 2; ++kc) {
      const int ch = kc * 4 + lg;
      short8 af[MF], bfr[NF];
#pragma unroll
      for (int mt = 0; mt < MF; ++mt) {
        int row = wm * (MF * 16) + mt * 16 + lr;
        af[mt] = *(const short8*)&As[row * 64 + ((ch ^ (row & 7)) * 8)];
      }
#pragma unroll
      for (int nt = 0; nt < NF; ++nt) {
        int row = wn * (NF * 16) + nt * 16 + lr;
        bfr[nt] = *(const short8*)&Bs[row * 64 + ((ch ^ (row & 7)) * 8)];
      }
#pragma unroll
      for (int mt = 0; mt < MF; ++mt)
#pragma unroll
        for (int nt = 0; nt < NF; ++nt)
          acc[mt][nt] = __builtin_amdgcn_mfma_f32_16x16x32_bf16(
              af[mt], bfr[nt], acc[mt][nt], 0, 0, 0);
    }
  }
}

// ---------------- fused Q/K/V/P projection GEMM (z = 0..3) ------------------
__global__ __launch_bounds__(256)
void gemm_qkvp(const u16* __restrict__ xbf, const u16* __restrict__ pebf,
               const u16* __restrict__ wt,
               const float* __restrict__ bq, const float* __restrict__ bk,
               const float* __restrict__ bv, const float* __restrict__ bp,
               const float* __restrict__ pbu, const float* __restrict__ pbv,
               u16* __restrict__ qu, u16* __restrict__ qv,
               u16* __restrict__ kk, u16* __restrict__ vt,
               u16* __restrict__ pp) {
  __shared__ __align__(16) u16 As[128 * 64];
  __shared__ __align__(16) u16 Bs[128 * 64];
  const int z = blockIdx.z;
  if (z == 3 && blockIdx.y >= 16) return;
  const u16* A = (z == 3) ? pebf : xbf;
  const u16* Bt = wt + (size_t)z * 512 * 512;
  const float* bias = (z == 0) ? bq : (z == 1) ? bk : (z == 2) ? bv : bp;
  const int m0 = blockIdx.y * 128, n0 = blockIdx.x * 128;

  f32x4 acc[4][4];
  gemm_core<4, 4>(A, Bt, m0, n0, As, Bs, acc);

  const int tid = threadIdx.x, wid = tid >> 6, lane = tid & 63;
  const int lr = lane & 15, lg = lane >> 4, wm = wid >> 1, wn = wid & 1;
#pragma unroll
  for (int mt = 0; mt < 4; ++mt)
#pragma unroll
    for (int nt = 0; nt < 4; ++nt) {
      const int col = n0 + wn * 64 + nt * 16 + lr;
      const int rb = m0 + wm * 64 + mt * 16 + lg * 4;
      const float bcol = bias[col];
      if (z == 0) {
        const float uu = pbu[col], vv = pbv[col];
#pragma unroll
        for (int q = 0; q < 4; ++q) {
          float val = acc[mt][nt][q] + bcol;
          qu[(size_t)(rb + q) * 512 + col] = f2bf(val + uu);
          qv[(size_t)(rb + q) * 512 + col] = f2bf(val + vv);
        }
      } else if (z == 1) {
#pragma unroll
        for (int q = 0; q < 4; ++q)
          kk[(size_t)(rb + q) * 512 + col] = f2bf(acc[mt][nt][q] + bcol);
      } else if (z == 2) {
        // V^T layout [b][h][d][t]
        ushort4 pk;
        pk.x = f2bf(acc[mt][nt][0] + bcol);
        pk.y = f2bf(acc[mt][nt][1] + bcol);
        pk.z = f2bf(acc[mt][nt][2] + bcol);
        pk.w = f2bf(acc[mt][nt][3] + bcol);
        int bb = rb >> 10, tl = rb & 1023;
        *(ushort4*)&vt[(size_t)((bb * 8 + (col >> 6)) * 64 + (col & 63)) * 1024 + tl] = pk;
      } else {
#pragma unroll
        for (int q = 0; q < 4; ++q)
          if (rb + q < 2047)
            pp[(size_t)(rb + q) * 512 + col] = f2bf(acc[mt][nt][q] + bcol);
      }
    }
}

// ---------------- output projection: out = ao @ Wo^T + bo (f32) -------------
__global__ __launch_bounds__(256)
void gemm_wo(const u16* __restrict__ ao, const u16* __restrict__ wt,
             const float* __restrict__ bo, float* __restrict__ out) {
  __shared__ __align__(16) u16 As[64 * 64];
  __shared__ __align__(16) u16 Bs[64 * 64];
  const int m0 = blockIdx.y * 64, n0 = blockIdx.x * 64;
  f32x4 acc[2][2];
  gemm_core<2, 2>(ao, wt + (size_t)4 * 512 * 512, m0, n0, As, Bs, acc);
  const int tid = threadIdx.x, wid = tid >> 6, lane = tid & 63;
  const int lr = lane & 15, lg = lane >> 4, wm = wid >> 1, wn = wid & 1;
#pragma unroll
  for (int mt = 0; mt < 2; ++mt)
#pragma unroll
    for (int nt = 0; nt < 2; ++nt) {
      const int col = n0 + wn * 32 + nt * 16 + lr;
      const int rb = m0 + wm * 32 + mt * 16 + lg * 4;
      const float bcol = bo[col];
#pragma unroll
      for (int q = 0; q < 4; ++q)
        out[(size_t)(rb + q) * 512 + col] = acc[mt][nt][q] + bcol;
    }
}

// ---------------- flash rel-pos attention, bf16 MFMA, transposed scores ------
// Block: 512 thr = 8 waves, 128 q-rows. Wave (grp = wid>>2, wq = wid&3):
// grp 0 -> even 64-col j-tiles, grp 1 -> odd; wq selects 32 rows (2 frags f).
// S^T = mfma(A=K, B=Qu): C col = t = lr, row = j = lg*4+q+16nt -> j lane-local
// in groups of 4 (Es write = b64; softmax = in-register; Bds write = b128).
__global__ __launch_bounds__(512)
void attn_mfma(const u16* __restrict__ quP, const u16* __restrict__ qvP,
               const u16* __restrict__ kP, const u16* __restrict__ vtP,
               const u16* __restrict__ pP, u16* __restrict__ ao) {
  // layout (u16 units): Ks[2] @0, Vs[2] @8192, Ps @16384, Wb @32768 (f32)
  __shared__ __align__(16) u16 SM[56832];
  u16* Ps = SM + 16384;

  const int tid = threadIdx.x;
  const int wid = tid >> 6, lane = tid & 63;
  const int lr = lane & 15, lg = lane >> 4;
  const int grp = wid >> 2, wq = wid & 3;
  const int t0 = blockIdx.x * 128, h = blockIdx.y, b = blockIdx.z;
  const int base0 = 896 - t0;  // P ring pos 0 <-> rel index base0

  u16* Ksg = SM + grp * 4096;
  u16* Vsg = SM + 8192 + grp * 4096;
  float* wbf = (float*)(SM + 32768) + wid * 1504;  // Bds_t [16][84] / Es overlay
  u16* esw = (u16*)wbf;

  // Q fragments: frag f covers rows t0 + 32*wq + 16*f .. +15 (B-operand now)
  short8 aqu[2][2], aqv[2][2];
#pragma unroll
  for (int f = 0; f < 2; ++f)
#pragma unroll
    for (int kc = 0; kc < 2; ++kc) {
      size_t g = (size_t)(b * SEQ + t0 + 32 * wq + 16 * f + lr) * 512 + h * 64 +
                 kc * 32 + lg * 8;
      aqu[f][kc] = *(const short8*)&quP[g];
      aqv[f][kc] = *(const short8*)&qvP[g];
    }
  short8 ones;
#pragma unroll
  for (int i = 0; i < 8; ++i) ones[i] = (short)0x3F80;  // bf16 1.0

  float mrun[2] = {-1e30f, -1e30f};  // per-lane running max (t = lr)
  f32x4 cL[2], cO[2][4];
#pragma unroll
  for (int f = 0; f < 2; ++f) {
    cL[f] = (f32x4)0.f;
#pragma unroll
    for (int nt = 0; nt < 4; ++nt) cO[f][nt] = (f32x4)0.f;
  }

  // ---- prologue staging: K/V j-rows 0..127, P ring rel base0..base0+255 ----
#pragma unroll
  for (int r = 0; r < 2; ++r) {
    int idx = tid + 512 * r;
    int row = idx >> 3, sc = idx & 7;
    short8 lk = *(const short8*)&kP[(size_t)(b * SEQ + row) * 512 + h * 64 + sc * 8];
    short8 lv = *(const short8*)&vtP[(size_t)((b * 8 + h) * 64 + (row & 63)) * 1024 +
                                     (row >> 6) * 64 + sc * 8];
    *(short8*)&SM[(row >> 6) * 4096 + (row & 63) * 64 + ((sc ^ (row & 7)) * 8)] = lk;
    *(short8*)&SM[8192 + (row >> 6) * 4096 + (row & 63) * 64 + ((sc ^ (row & 7)) * 8)] = lv;
  }
#pragma unroll
  for (int r = 0; r < 4; ++r) {
    int idx = tid + 512 * r;
    int prow = idx >> 3, sc = idx & 7;  // 0..255
    short8 lp = *(const short8*)&pP[(size_t)(base0 + prow) * 512 + h * 64 + sc * 8];
    *(short8*)&Ps[prow * 64 + ((sc ^ (prow & 7)) * 8)] = lp;
  }
  __syncthreads();

  for (int s = 0; s < 8; ++s) {
    // ---- T14: issue next superstep's global loads early ----
    short8 nk[2], nv[2], np[2];
    if (s < 7) {
      const int jn = 128 * (s + 1);
#pragma unroll
      for (int r = 0; r < 2; ++r) {
        int idx = tid + 512 * r;
        int row = idx >> 3, sc = idx & 7;
        nk[r] = *(const short8*)&kP[(size_t)(b * SEQ + jn + row) * 512 + h * 64 + sc * 8];
        nv[r] = *(const short8*)&vtP[(size_t)((b * 8 + h) * 64 + (row & 63)) * 1024 +
                                     jn + (row >> 6) * 64 + sc * 8];
        np[r] = *(const short8*)&pP[(size_t)(base0 + 256 + 128 * s + row) * 512 +
                                    h * 64 + sc * 8];
      }
    }

    // ---- S^T = mfma(A=K, B=Qu): row=j(lg*4+q+16nt), col=t(lr) ----
    f32x4 cKT[2][4];
#pragma unroll
    for (int f = 0; f < 2; ++f)
#pragma unroll
      for (int nt = 0; nt < 4; ++nt) cKT[f][nt] = (f32x4)0.f;
    __builtin_amdgcn_s_setprio(1);
#pragma unroll
    for (int kc = 0; kc < 2; ++kc) {
      const int ch = kc * 4 + lg;
#pragma unroll
      for (int nt = 0; nt < 4; ++nt) {
        int krow = nt * 16 + lr;
        short8 bk = *(const short8*)&Ksg[krow * 64 + ((ch ^ (krow & 7)) * 8)];
        cKT[0][nt] = __builtin_amdgcn_mfma_f32_16x16x32_bf16(bk, aqu[0][kc], cKT[0][nt], 0, 0, 0);
        cKT[1][nt] = __builtin_amdgcn_mfma_f32_16x16x32_bf16(bk, aqu[1][kc], cKT[1][nt], 0, 0, 0);
      }
    }
    __builtin_amdgcn_s_setprio(0);

    // ---- hoist V fragments (each feeds both f's PV) ----
    short8 bvr[2][4];
#pragma unroll
    for (int kc = 0; kc < 2; ++kc) {
      const int ch = kc * 4 + lg;
#pragma unroll
      for (int nt = 0; nt < 4; ++nt) {
        int vr = nt * 16 + lr;
        bvr[kc][nt] = *(const short8*)&Vsg[vr * 64 + ((ch ^ (vr & 7)) * 8)];
      }
    }

#pragma unroll
    for (int f = 0; f < 2; ++f) {
      // window: ring pos = (poff + w) & 255, w = winpos 0..79
      const int poff = 112 - 32 * wq - 16 * f + 64 * grp + 128 * s;
      // cP^T = mfma(A=P, B=Qv): row = w (lg*4+q+16pt), col = t (lr)
      f32x4 cPT[5];
#pragma unroll
      for (int i = 0; i < 5; ++i) cPT[i] = (f32x4)0.f;
      __builtin_amdgcn_s_setprio(1);
#pragma unroll
      for (int kc = 0; kc < 2; ++kc) {
        const int ch = kc * 4 + lg;
        const int swz = (ch ^ (lr & 7)) * 8;  // pos & 7 == lr & 7
#pragma unroll
        for (int pt = 0; pt < 5; ++pt) {
          int pos = (poff + pt * 16 + lr) & 255;
          short8 bp = *(const short8*)&Ps[pos * 64 + swz];
          cPT[pt] = __builtin_amdgcn_mfma_f32_16x16x32_bf16(bp, aqv[f][kc], cPT[pt], 0, 0, 0);
        }
      }
      __builtin_amdgcn_s_setprio(0);

      // ---- Bds_t [t=lr][w:84]: b128 writes (4 q-consecutive w per reg) ----
#pragma unroll
      for (int pt = 0; pt < 5; ++pt)
        *(f32x4*)&wbf[lr * 84 + pt * 16 + lg * 4] = cPT[pt];
      // read shifted: w = j + 15 - t_local = 16nt + lg*4 + q + 15 - lr
      float sv[4][4];
#pragma unroll
      for (int nt = 0; nt < 4; ++nt)
#pragma unroll
        for (int q = 0; q < 4; ++q)
          sv[nt][q] = 0.125f * (cKT[f][nt][q] +
                                wbf[lr * 84 + 16 * nt + lg * 4 + q + 15 - lr]);

      // ---- per-lane softmax (t = lr): in-reg max + 2 cross-lane ----
      float tm = sv[0][0];
#pragma unroll
      for (int nt = 0; nt < 4; ++nt)
#pragma unroll
        for (int q = 0; q < 4; ++q) tm = fmaxf(tm, sv[nt][q]);
      tm = fmaxf(tm, __shfl_xor(tm, 16));
      tm = fmaxf(tm, __shfl_xor(tm, 32));
      // defer-max (THR=8)
      if (__any(tm > mrun[f] + 8.f)) {
        float mnew = fmaxf(mrun[f], tm);
        float corr = __expf(mrun[f] - mnew);
        mrun[f] = mnew;
        // corr lives at t=lr; C rows are t=lg*4+q -> transpose via shfl (rare)
        float cc[4];
#pragma unroll
        for (int q = 0; q < 4; ++q)
          cc[q] = __shfl(corr, (lane & 48) | (lg * 4 + q));
#pragma unroll
        for (int q = 0; q < 4; ++q) {
          cL[f][q] *= cc[q];
#pragma unroll
          for (int nt = 0; nt < 4; ++nt) cO[f][nt][q] *= cc[q];
        }
      }

      // ---- exp -> bf16 -> Es_T: 4 swizzled b64 writes (j lane-local!) ----
#pragma unroll
      for (int nt = 0; nt < 4; ++nt) {
        float e0 = __expf(sv[nt][0] - mrun[f]);
        float e1 = __expf(sv[nt][1] - mrun[f]);
        float e2 = __expf(sv[nt][2] - mrun[f]);
        float e3 = __expf(sv[nt][3] - mrun[f]);
        uint2 pk;
        pk.x = (u32)f2bf(e0) | ((u32)f2bf(e1) << 16);
        pk.y = (u32)f2bf(e2) | ((u32)f2bf(e3) << 16);
        int g = 2 * nt + (lg >> 1);  // j-granule (8 u16)
        *(uint2*)&esw[lr * 64 + ((g ^ (lr & 7)) * 8) + (lg & 1) * 4] = pk;
      }

      // ---- PV + denominator: pa = E A-frag (row=t=lr, k=j) ----
      __builtin_amdgcn_s_setprio(1);
#pragma unroll
      for (int kc = 0; kc < 2; ++kc) {
        const int ch = kc * 4 + lg;
        short8 pa = *(const short8*)&esw[lr * 64 + ((ch ^ (lr & 7)) * 8)];
        cL[f] = __builtin_amdgcn_mfma_f32_16x16x32_bf16(pa, ones, cL[f], 0, 0, 0);
#pragma unroll
        for (int nt = 0; nt < 4; ++nt)
          cO[f][nt] = __builtin_amdgcn_mfma_f32_16x16x32_bf16(pa, bvr[kc][nt], cO[f][nt], 0, 0, 0);
      }
      __builtin_amdgcn_s_setprio(0);
    }

    __syncthreads();
    // ---- write staged tiles for next superstep ----
    if (s < 7) {
#pragma unroll
      for (int r = 0; r < 2; ++r) {
        int idx = tid + 512 * r;
        int row = idx >> 3, sc = idx & 7;
        *(short8*)&SM[(row >> 6) * 4096 + (row & 63) * 64 + ((sc ^ (row & 7)) * 8)] = nk[r];
        *(short8*)&SM[8192 + (row >> 6) * 4096 + (row & 63) * 64 + ((sc ^ (row & 7)) * 8)] = nv[r];
        int pos = (128 * s + row) & 255;
        *(short8*)&Ps[pos * 64 + ((sc ^ (pos & 7)) * 8)] = np[r];
      }
    }
    __syncthreads();
  }

  // ---- transpose m to C-layout rows (once) ----
  float m_c[2][4];
#pragma unroll
  for (int f = 0; f < 2; ++f)
#pragma unroll
    for (int q = 0; q < 4; ++q)
      m_c[f][q] = __shfl(mrun[f], (lane & 48) | (lg * 4 + q));

  // ---- merge j-halves (exact flash merge) via LDS overlay ----
  float* ob = (float*)SM;             // 128 x 64 f32 (Ks+Vs region)
  float* mlb = (float*)(SM + 16384);  // 128 x {m,l} (Ps region)
  if (grp == 1) {
#pragma unroll
    for (int f = 0; f < 2; ++f) {
#pragma unroll
      for (int nt = 0; nt < 4; ++nt)
#pragma unroll
        for (int q = 0; q < 4; ++q)
          ob[(wq * 32 + 16 * f + 4 * lg + q) * 64 + nt * 16 + lr] = cO[f][nt][q];
      if (lr == 0) {
#pragma unroll
        for (int q = 0; q < 4; ++q) {
          int rr = wq * 32 + 16 * f + 4 * lg + q;
          mlb[rr * 2 + 0] = m_c[f][q];
          mlb[rr * 2 + 1] = cL[f][q];
        }
      }
    }
  }
  __syncthreads();
  if (grp == 0) {
#pragma unroll
    for (int f = 0; f < 2; ++f) {
      float ws0[4], ws1[4];
#pragma unroll
      for (int q = 0; q < 4; ++q) {
        int rr = wq * 32 + 16 * f + 4 * lg + q;
        float m1 = mlb[rr * 2 + 0], l1 = mlb[rr * 2 + 1];
        float M = fmaxf(m_c[f][q], m1);
        float w0 = __expf(m_c[f][q] - M), w1 = __expf(m1 - M);
        float inv = 1.f / (w0 * cL[f][q] + w1 * l1);
        ws0[q] = w0 * inv;
        ws1[q] = w1 * inv;
      }
#pragma unroll
      for (int nt = 0; nt < 4; ++nt)
#pragma unroll
        for (int q = 0; q < 4; ++q) {
          int rr = wq * 32 + 16 * f + 4 * lg + q;
          float o1 = ob[rr * 64 + nt * 16 + lr];
          float val = ws0[q] * cO[f][nt][q] + ws1[q] * o1;
          ao[(size_t)(b * SEQ + t0 + rr) * 512 + h * 64 + nt * 16 + lr] = f2bf(val);
        }
    }
  }
}

extern "C" void kernel_launch(void* const* d_in, const int* in_sizes, int n_in,
                              void* d_out, int out_size, void* d_ws, size_t ws_size,
                              hipStream_t stream) {
  const float* x   = (const float*)d_in[0];
  const float* pe  = (const float*)d_in[1];
  const float* Wq  = (const float*)d_in[2];
  const float* bq  = (const float*)d_in[3];
  const float* Wk  = (const float*)d_in[4];
  const float* bk  = (const float*)d_in[5];
  const float* Wv  = (const float*)d_in[6];
  const float* bv  = (const float*)d_in[7];
  const float* Wp  = (const float*)d_in[8];
  const float* bp  = (const float*)d_in[9];
  const float* Wo  = (const float*)d_in[10];
  const float* bo  = (const float*)d_in[11];
  const float* pbu = (const float*)d_in[12];
  const float* pbv = (const float*)d_in[13];

  char* ws = (char*)d_ws;
  size_t o = 0;
  auto alloc = [&](size_t bytes) { size_t r = o; o += (bytes + 255) & ~(size_t)255; return r; };
  u16* x_bf  = (u16*)(ws + alloc((size_t)4096 * 512 * 2));
  u16* pe_bf = (u16*)(ws + alloc((size_t)2048 * 512 * 2));
  u16* wt    = (u16*)(ws + alloc((size_t)5 * 512 * 512 * 2));
  u16* qu    = (u16*)(ws + alloc((size_t)4096 * 512 * 2));
  u16* qv    = (u16*)(ws + alloc((size_t)4096 * 512 * 2));
  u16* kk    = (u16*)(ws + alloc((size_t)4096 * 512 * 2));
  u16* vt    = (u16*)(ws + alloc((size_t)4096 * 512 * 2));
  u16* pp    = (u16*)(ws + alloc((size_t)2048 * 512 * 2));
  u16* ao    = (u16*)(ws + alloc((size_t)4096 * 512 * 2));

  dim3 blk(256);
  cvt_two<<<dim3(3072), blk, 0, stream>>>(x, pe, x_bf, pe_bf);
  transpose_w<<<dim3(16, 16, 5), dim3(32, 8), 0, stream>>>(Wq, Wk, Wv, Wp, Wo, wt);
  hipMemsetAsync(pp + (size_t)2047 * 512, 0, 512 * 2, stream);

  gemm_qkvp<<<dim3(4, 32, 4), blk, 0, stream>>>(x_bf, pe_bf, wt, bq, bk, bv, bp,
                                                pbu, pbv, qu, qv, kk, vt, pp);
  attn_mfma<<<dim3(8, NHEAD, BATCH), dim3(512), 0, stream>>>(qu, qv, kk, vt, pp, ao);
  gemm_wo<<<dim3(8, 64), blk, 0, stream>>>(ao, wt, bo, (float*)d_out);
}